// Round 19
// baseline (100.821 us; speedup 1.0000x reference)
//
#include <hip/hip_runtime.h>
#include <hip/hip_bf16.h>
#include <stdint.h>
#include <math.h>

#define SLEN 512
#define NT 48
#define TAG_START 46
#define TAG_STOP 47

// workspace layout (floats)
#define WS_QF 0        // [b*64 + 0..47] q_m ; +48 cbits_f ; +49 gold_full
#define WS_WB 65536    // [b*64 + 0..47] w_m ; +48 cbits_b
#define WS_OUT 131072  // [b] per-batch (logZ - gold)

// batch-1 LDS region offset: 1552 ≡ 16 (mod 32) floats -> banks 16..31,
// disjoint from batch-0 (banks 0..15) at every row. Kills R18's 2.6M conflicts.
#define B1OFF 1552

typedef __attribute__((ext_vector_type(8))) short bf16x8;
typedef __attribute__((ext_vector_type(4))) float f32x4;

typedef const uint32_t __attribute__((address_space(1)))* gptr_t;
typedef uint32_t __attribute__((address_space(3)))* lptr_t;

__device__ __forceinline__ void gload16(const float* g, float* l) {
  __builtin_amdgcn_global_load_lds((gptr_t)(uintptr_t)g, (lptr_t)(uintptr_t)l,
                                   16, 0, 0);
}
// Truncation pack (R14-proven): one v_perm_b32.
__device__ __forceinline__ uint32_t pk2(float a, float b) {
  return __builtin_amdgcn_perm(__float_as_uint(b), __float_as_uint(a),
                               0x07060302u);
}
__device__ __forceinline__ float fmax4(f32x4 v) {
  return fmaxf(fmaxf(v.x, v.y), fmaxf(v.z, v.w));
}

// 1024 blocks = (pair p, dir). One chain direction for TWO batches
// (B-columns 0,1). 1 wave/SIMD, ~len/2 depth, 6 MFMA/step.
__global__ __launch_bounds__(64) void crf_split2_kernel(
    const float* __restrict__ em, const int* __restrict__ tags,
    const int* __restrict__ mask, const float* __restrict__ Tr,
    float* __restrict__ ws) {
  const int bid = blockIdx.x;
  const int dir = bid & 1;
  const int p = bid >> 1;
  const int b0 = 2 * p, b1 = 2 * p + 1;
  const int lane = threadIdx.x;
  const int g = lane >> 4;
  const int n = lane & 15;
  __shared__ __align__(16) float sbuf[2][B1OFF + 32 * NT];  // ~24.7 KB

  // lengths of both batches (prefix masks)
  int len0, len1;
  {
    int lc0 = 0, lc1 = 0;
    const int* r0 = mask + (size_t)b0 * SLEN;
    const int* r1 = mask + (size_t)b1 * SLEN;
    for (int t = lane; t < SLEN; t += 64) {
      lc0 += r0[t];
      lc1 += r1[t];
    }
#pragma unroll
    for (int d = 32; d >= 1; d >>= 1) {
      lc0 += __shfl_xor(lc0, d);
      lc1 += __shfl_xor(lc1, d);
    }
    len0 = lc0;
    len1 = lc1;
  }
  const int m0 = len0 >> 1, m1 = len1 >> 1;
  const int st0 = dir ? (len0 - m0) : m0;
  const int st1 = dir ? (len1 - m1) : m1;
  const int smax = (st0 > st1) ? st0 : st1;
  const int my_st = (n == 0) ? st0 : ((n == 1) ? st1 : 0);  // 0: never latch

  // A fragments: dir0 rows of E^T (R8-verified), dir1 rows of E (R10-verified)
  bf16x8 A[3][2];
#pragma unroll
  for (int t = 0; t < 3; ++t) {
#pragma unroll
    for (int c = 0; c < 2; ++c) {
      union { uint32_t u[4]; bf16x8 v; } tmp;
#pragma unroll
      for (int ep = 0; ep < 4; ++ep) {
        float fe[2];
#pragma unroll
        for (int h = 0; h < 2; ++h) {
          const int e = 2 * ep + h;
          const int kl = (e < 4) ? (4 * g + e) : (16 + 4 * g + (e - 4));
          const int ig = 32 * c + kl;
          fe[h] = 0.0f;
          if (ig < NT)
            fe[h] = dir ? __expf(Tr[(16 * t + n) * NT + ig])
                        : __expf(Tr[ig * NT + 16 * t + n]);
        }
        tmp.u[ep] = pk2(fe[0], fe[1]);
      }
      A[t][c] = tmp.v;
    }
  }

  const f32x4 z4 = {0.f, 0.f, 0.f, 0.f};
  // state: column n carries batch (n==0 ? b0 : b1); cols 2-15 stay zero
  f32x4 v0 = z4, v1 = z4, v2 = z4;
  if (dir == 0) {
    if (n < 2 && g == 3) v2.z = 1.0f;  // one-hot START=46 per column
  } else {
    if (n < 2) {
      const f32x4 one4 = {1.f, 1.f, 1.f, 1.f};
      v0 = one4;
      v1 = one4;
      v2 = one4;
    }
  }
  int cbits = 0;
  f32x4 sv0 = z4, sv1 = z4, sv2 = z4;  // latched state
  int scb = 0;

  const float* eb0 = em + (size_t)b0 * SLEN * NT;
  const float* eb1 = em + (size_t)b1 * SLEN * NT;
  const int myoff = (n == 1) ? B1OFF : 0;  // per-lane batch region

  const int nwin = (smax + 31) >> 5;  // 32*nwin <= 256+31 < min(len) rows safe

  // stage window 0 for both batches
  {
    const float* s0 = dir ? (eb0 + (size_t)(len0 - 32) * NT) : eb0;
    const float* s1 = dir ? (eb1 + (size_t)(len1 - 32) * NT) : eb1;
#pragma unroll
    for (int k = 0; k < 6; ++k) {
      gload16(s0 + k * 256 + lane * 4, &sbuf[0][k * 256]);
      gload16(s1 + k * 256 + lane * 4, &sbuf[0][B1OFF + k * 256]);
    }
  }

  float mxp = 1.0f;  // pending renorm max (issued 2 steps before apply)
  int rc = 0;        // step counter within the 6-step renorm cycle

  for (int c = 0; c < nwin; ++c) {
    asm volatile("s_waitcnt vmcnt(0)" ::: "memory");
    if (c + 1 < nwin) {
      const float* s0 = dir ? (eb0 + (size_t)(len0 - 32 * (c + 2)) * NT)
                            : (eb0 + (size_t)(32 * (c + 1)) * NT);
      const float* s1 = dir ? (eb1 + (size_t)(len1 - 32 * (c + 2)) * NT)
                            : (eb1 + (size_t)(32 * (c + 1)) * NT);
#pragma unroll
      for (int k = 0; k < 6; ++k) {
        gload16(s0 + k * 256 + lane * 4, &sbuf[(c + 1) & 1][k * 256]);
        gload16(s1 + k * 256 + lane * 4, &sbuf[(c + 1) & 1][B1OFF + k * 256]);
      }
    }
    // pre-exp both regions, flat indexing (2-way alias = free)
    {
      float* base = &sbuf[c & 1][0];
#pragma unroll
      for (int r = 0; r < 6; ++r) {
        f32x4* pp = (f32x4*)(base + r * 256 + lane * 4);
        f32x4 vx = *pp;
        vx.x = __expf(vx.x);
        vx.y = __expf(vx.y);
        vx.z = __expf(vx.z);
        vx.w = __expf(vx.w);
        *pp = vx;
        f32x4* p2 = (f32x4*)(base + B1OFF + r * 256 + lane * 4);
        f32x4 vy = *p2;
        vy.x = __expf(vy.x);
        vy.y = __expf(vy.y);
        vy.z = __expf(vy.z);
        vy.w = __expf(vy.w);
        *p2 = vy;
      }
    }
    const int steps = (smax - 32 * c < 32) ? (smax - 32 * c) : 32;
    for (int sl = 0; sl < steps; ++sl) {
      const int s = 32 * c + sl;
      const int local = dir ? (31 - sl) : sl;
      const float* xb = &sbuf[c & 1][myoff + local * NT];
      const f32x4 x0 = *(const f32x4*)(xb + 4 * g);
      const f32x4 x1 = *(const f32x4*)(xb + 16 + 4 * g);
      const f32x4 x2 = *(const f32x4*)(xb + 32 + 4 * g);
      union { uint32_t u[4]; bf16x8 v; } B0, B1;
      if (dir == 0) {
        B0.u[0] = pk2(v0.x, v0.y);
        B0.u[1] = pk2(v0.z, v0.w);
        B0.u[2] = pk2(v1.x, v1.y);
        B0.u[3] = pk2(v1.z, v1.w);
        B1.u[0] = pk2(v2.x, v2.y);
        B1.u[1] = pk2(v2.z, v2.w);
        B1.u[2] = 0u;
        B1.u[3] = 0u;
      } else {  // bwd: y = v∘x packed, post-state is raw matvec
        const f32x4 y0 = v0 * x0, y1 = v1 * x1, y2 = v2 * x2;
        B0.u[0] = pk2(y0.x, y0.y);
        B0.u[1] = pk2(y0.z, y0.w);
        B0.u[2] = pk2(y1.x, y1.y);
        B0.u[3] = pk2(y1.z, y1.w);
        B1.u[0] = pk2(y2.x, y2.y);
        B1.u[1] = pk2(y2.z, y2.w);
        B1.u[2] = 0u;
        B1.u[3] = 0u;
      }
      f32x4 a0 = __builtin_amdgcn_mfma_f32_16x16x32_bf16(A[0][0], B0.v, z4, 0, 0, 0);
      f32x4 a1 = __builtin_amdgcn_mfma_f32_16x16x32_bf16(A[1][0], B0.v, z4, 0, 0, 0);
      f32x4 a2 = __builtin_amdgcn_mfma_f32_16x16x32_bf16(A[2][0], B0.v, z4, 0, 0, 0);
      a0 = __builtin_amdgcn_mfma_f32_16x16x32_bf16(A[0][1], B1.v, a0, 0, 0, 0);
      a1 = __builtin_amdgcn_mfma_f32_16x16x32_bf16(A[1][1], B1.v, a1, 0, 0, 0);
      a2 = __builtin_amdgcn_mfma_f32_16x16x32_bf16(A[2][1], B1.v, a2, 0, 0, 0);
      if (dir == 0) {
        v0 = a0 * x0;
        v1 = a1 * x1;
        v2 = a2 * x2;
      } else {
        v0 = a0;
        v1 = a1;
        v2 = a2;
      }
      // Deferred per-column renorm: issue reduce at rc==4, apply at rc==6.
      // Scale commutes with the linear recurrence, so the 2-step delay is
      // exact; DS latency of the shuffles hides under 2 steps of MFMA work.
      ++rc;
      if (rc == 4) {
        float mx = fmaxf(fmax4(__builtin_elementwise_max(
                             __builtin_elementwise_max(v0, v1), v2)),
                         1e-30f);
        mx = fmaxf(mx, __shfl_xor(mx, 16));
        mx = fmaxf(mx, __shfl_xor(mx, 32));
        mxp = mx;
      } else if (rc == 6) {
        const int ex = ((__float_as_int(mxp) >> 23) & 255) - 126;
        const float sc = __int_as_float((127 - ex) << 23);
        v0 *= sc;
        v1 *= sc;
        v2 *= sc;
        cbits += ex;
        rc = 0;
      }
      if (s + 1 == st0 || s + 1 == st1) {  // wave-uniform, rare (~2/256)
        const bool L = (n < 2) && (s + 1 == my_st);
        sv0 = L ? v0 : sv0;
        sv1 = L ? v1 : sv1;
        sv2 = L ? v2 : sv2;
        scb = L ? cbits : scb;
      }
    }
  }

  // store latched states (cols 0,1 -> batches b0,b1)
  if (n < 2) {
    const int bb = n ? b1 : b0;
    float* dst = ws + (dir ? WS_WB : WS_QF) + (size_t)bb * 64;
    *(f32x4*)(dst + 4 * g) = sv0;
    *(f32x4*)(dst + 16 + 4 * g) = sv1;
    *(f32x4*)(dst + 32 + 4 * g) = sv2;
    if (g == 0) dst[48] = (float)scb;
  }

  if (dir == 0) {  // gold scores for both batches
#pragma unroll
    for (int which = 0; which < 2; ++which) {
      const int bb = which ? b1 : b0;
      const int ll = which ? len1 : len0;
      const float* eb = which ? eb1 : eb0;
      const int* trow = tags + (size_t)bb * SLEN;
      float gsc = 0.f;
      for (int t = lane; t < ll; t += 64) {
        const int tag = trow[t];
        const int prev = (t == 0) ? TAG_START : trow[t - 1];
        gsc += Tr[tag * NT + prev] + eb[(size_t)t * NT + tag];
      }
#pragma unroll
      for (int d = 32; d >= 1; d >>= 1) gsc += __shfl_xor(gsc, d);
      if (lane == 0) {
        const int last = trow[ll - 1];
        ws[WS_QF + (size_t)bb * 64 + 49] = gsc + Tr[TAG_STOP * NT + last];
      }
    }
  }
}

// Per-batch: logZ - gold = log(q·w) + cbits*ln2 + T[STOP][0] - gold_full.
__global__ __launch_bounds__(64) void crf_combine_kernel(
    const float* __restrict__ Tr, float* __restrict__ ws) {
  const int b = blockIdx.x;
  const int lane = threadIdx.x;
  float p = 0.f;
  if (lane < NT)
    p = ws[WS_QF + (size_t)b * 64 + lane] * ws[WS_WB + (size_t)b * 64 + lane];
#pragma unroll
  for (int d = 32; d >= 1; d >>= 1) p += __shfl_xor(p, d);
  if (lane == 0) {
    const float cb =
        ws[WS_QF + (size_t)b * 64 + 48] + ws[WS_WB + (size_t)b * 64 + 48];
    const float gold = ws[WS_QF + (size_t)b * 64 + 49];
    ws[WS_OUT + b] =
        __logf(p) + cb * 0.69314718055994531f + Tr[TAG_STOP * NT] - gold;
  }
}

// Deterministic tree-mean over B values (no atomics).
__global__ void crf_reduce_kernel(const float* __restrict__ wsrc,
                                  float* __restrict__ out, int nn) {
  const int tid = threadIdx.x;
  float v = (tid < nn) ? wsrc[tid] : 0.f;
#pragma unroll
  for (int d = 32; d >= 1; d >>= 1) v += __shfl_xor(v, d);
  __shared__ float part[16];
  if ((tid & 63) == 0) part[tid >> 6] = v;
  __syncthreads();
  if (tid == 0) {
    float s = 0.f;
    for (int i = 0; i < 16; ++i) s += part[i];
    out[0] = s / (float)nn;
  }
}

extern "C" void kernel_launch(void* const* d_in, const int* in_sizes, int n_in,
                              void* d_out, int out_size, void* d_ws, size_t ws_size,
                              hipStream_t stream) {
  const float* em = (const float*)d_in[0];
  const int* tags = (const int*)d_in[1];
  const int* mask = (const int*)d_in[2];
  const float* Tr = (const float*)d_in[3];
  const int B = in_sizes[0] / (SLEN * NT);  // 1024

  float* ws = (float*)d_ws;  // 132096 floats ≈ 528 KB
  crf_split2_kernel<<<B, 64, 0, stream>>>(em, tags, mask, Tr, ws);
  crf_combine_kernel<<<B, 64, 0, stream>>>(Tr, ws);
  crf_reduce_kernel<<<1, 1024, 0, stream>>>(ws + WS_OUT, (float*)d_out, B);
}

// Round 21
// 84.424 us; speedup vs baseline: 1.1942x; 1.1942x over previous
//
#include <hip/hip_runtime.h>
#include <hip/hip_bf16.h>
#include <stdint.h>
#include <math.h>

#define SLEN 512
#define NT 48
#define TAG_START 46
#define TAG_STOP 47

// workspace layout (floats)
#define WS_QF 0        // [b*64 + 0..47] q_m ; +48 cbits_f ; +49 gold_full
#define WS_WB 65536    // [b*64 + 0..47] w_m ; +48 cbits_b
#define WS_OUT 131072  // [b] per-batch (logZ - gold)

// batch-1 LDS region offset: 1552 ≡ 16 (mod 32) floats -> banks 16..31,
// disjoint from batch-0 (banks 0..15). R19-verified: conflicts -> 0.
#define B1OFF 1552

typedef __attribute__((ext_vector_type(8))) short bf16x8;
typedef __attribute__((ext_vector_type(4))) float f32x4;

typedef const uint32_t __attribute__((address_space(1)))* gptr_t;
typedef uint32_t __attribute__((address_space(3)))* lptr_t;

__device__ __forceinline__ void gload16(const float* g, float* l) {
  __builtin_amdgcn_global_load_lds((gptr_t)(uintptr_t)g, (lptr_t)(uintptr_t)l,
                                   16, 0, 0);
}
// Truncation pack (R14-proven): one v_perm_b32.
__device__ __forceinline__ uint32_t pk2(float a, float b) {
  return __builtin_amdgcn_perm(__float_as_uint(b), __float_as_uint(a),
                               0x07060302u);
}
__device__ __forceinline__ float fmax4(f32x4 v) {
  return fmaxf(fmaxf(v.x, v.y), fmaxf(v.z, v.w));
}
__device__ __forceinline__ f32x4 exp4(f32x4 v) {
  v.x = __expf(v.x);
  v.y = __expf(v.y);
  v.z = __expf(v.z);
  v.w = __expf(v.w);
  return v;
}

// 1024 blocks = (pair p, dir). One chain direction for TWO batches
// (B-columns 0,1). Meet point m_b = (len_b>>1) & ~7 -> both chains' main
// step counts are multiples of 8 (backward after a <=7-step prologue), so
// latching happens ONLY at group ends (branchless cndmask). Main loop is
// pure R8-style unrolled groups: no data-dependent control flow.
__global__ __launch_bounds__(64) void crf_split2_kernel(
    const float* __restrict__ em, const int* __restrict__ tags,
    const int* __restrict__ mask, const float* __restrict__ Tr,
    float* __restrict__ ws) {
  const int bid = blockIdx.x;
  const int dir = bid & 1;
  const int pr = bid >> 1;
  const int b0 = 2 * pr, b1 = 2 * pr + 1;
  const int lane = threadIdx.x;
  const int g = lane >> 4;
  const int n = lane & 15;
  __shared__ __align__(16) float sbuf[2][B1OFF + 32 * NT];  // ~24.7 KB

  // lengths of both batches (prefix masks)
  int len0, len1;
  {
    int lc0 = 0, lc1 = 0;
    const int* r0 = mask + (size_t)b0 * SLEN;
    const int* r1 = mask + (size_t)b1 * SLEN;
    for (int t = lane; t < SLEN; t += 64) {
      lc0 += r0[t];
      lc1 += r1[t];
    }
#pragma unroll
    for (int d = 32; d >= 1; d >>= 1) {
      lc0 += __shfl_xor(lc0, d);
      lc1 += __shfl_xor(lc1, d);
    }
    len0 = lc0;
    len1 = lc1;
  }
  // meet points (multiples of 8); len' = len & ~7; prologue p_j = len_j & 7
  const int m0 = (len0 >> 1) & ~7, m1 = (len1 >> 1) & ~7;
  const int lp0 = len0 & ~7, lp1 = len1 & ~7;
  const int p0 = len0 & 7, p1 = len1 & 7;
  // main-loop step counts (all multiples of 8, in [128, 256])
  const int stm0 = dir ? (lp0 - m0) : m0;
  const int stm1 = dir ? (lp1 - m1) : m1;
  const int smax = (stm0 > stm1) ? stm0 : stm1;
  const int my_stm = (n == 0) ? stm0 : ((n == 1) ? stm1 : -1);

  // A fragments: dir0 rows of E^T (R8-verified), dir1 rows of E (R10-verified)
  bf16x8 A[3][2];
#pragma unroll
  for (int t = 0; t < 3; ++t) {
#pragma unroll
    for (int c = 0; c < 2; ++c) {
      union { uint32_t u[4]; bf16x8 v; } tmp;
#pragma unroll
      for (int ep = 0; ep < 4; ++ep) {
        float fe[2];
#pragma unroll
        for (int h = 0; h < 2; ++h) {
          const int e = 2 * ep + h;
          const int kl = (e < 4) ? (4 * g + e) : (16 + 4 * g + (e - 4));
          const int ig = 32 * c + kl;
          fe[h] = 0.0f;
          if (ig < NT)
            fe[h] = dir ? __expf(Tr[(16 * t + n) * NT + ig])
                        : __expf(Tr[ig * NT + 16 * t + n]);
        }
        tmp.u[ep] = pk2(fe[0], fe[1]);
      }
      A[t][c] = tmp.v;
    }
  }

  const f32x4 z4 = {0.f, 0.f, 0.f, 0.f};
  // state: column n carries batch (n==0 ? b0 : b1); cols 2-15 stay zero
  f32x4 v0 = z4, v1 = z4, v2 = z4;
  if (dir == 0) {
    if (n < 2 && g == 3) v2.z = 1.0f;  // one-hot START=46 per column
  } else {
    if (n < 2) {
      const f32x4 one4 = {1.f, 1.f, 1.f, 1.f};
      v0 = one4;
      v1 = one4;
      v2 = one4;
    }
  }
  int cbits = 0;
  f32x4 sv0 = z4, sv1 = z4, sv2 = z4;  // latched state
  int scb = 0;

  const float* eb0 = em + (size_t)b0 * SLEN * NT;
  const float* eb1 = em + (size_t)b1 * SLEN * NT;
  const int myoff = (n == 1) ? B1OFF : 0;

  // one step given explicit x vectors (R12-proven by-value pattern)
  auto dostep_x = [&](f32x4 x0, f32x4 x1, f32x4 x2) {
    union { uint32_t u[4]; bf16x8 v; } B0, B1;
    if (dir == 0) {
      B0.u[0] = pk2(v0.x, v0.y);
      B0.u[1] = pk2(v0.z, v0.w);
      B0.u[2] = pk2(v1.x, v1.y);
      B0.u[3] = pk2(v1.z, v1.w);
      B1.u[0] = pk2(v2.x, v2.y);
      B1.u[1] = pk2(v2.z, v2.w);
      B1.u[2] = 0u;
      B1.u[3] = 0u;
    } else {  // bwd: y = v∘x packed; post-state is raw matvec
      const f32x4 y0 = v0 * x0, y1 = v1 * x1, y2 = v2 * x2;
      B0.u[0] = pk2(y0.x, y0.y);
      B0.u[1] = pk2(y0.z, y0.w);
      B0.u[2] = pk2(y1.x, y1.y);
      B0.u[3] = pk2(y1.z, y1.w);
      B1.u[0] = pk2(y2.x, y2.y);
      B1.u[1] = pk2(y2.z, y2.w);
      B1.u[2] = 0u;
      B1.u[3] = 0u;
    }
    f32x4 a0 = __builtin_amdgcn_mfma_f32_16x16x32_bf16(A[0][0], B0.v, z4, 0, 0, 0);
    f32x4 a1 = __builtin_amdgcn_mfma_f32_16x16x32_bf16(A[1][0], B0.v, z4, 0, 0, 0);
    f32x4 a2 = __builtin_amdgcn_mfma_f32_16x16x32_bf16(A[2][0], B0.v, z4, 0, 0, 0);
    a0 = __builtin_amdgcn_mfma_f32_16x16x32_bf16(A[0][1], B1.v, a0, 0, 0, 0);
    a1 = __builtin_amdgcn_mfma_f32_16x16x32_bf16(A[1][1], B1.v, a1, 0, 0, 0);
    a2 = __builtin_amdgcn_mfma_f32_16x16x32_bf16(A[2][1], B1.v, a2, 0, 0, 0);
    if (dir == 0) {
      v0 = a0 * x0;
      v1 = a1 * x1;
      v2 = a2 * x2;
    } else {
      v0 = a0;
      v1 = a1;
      v2 = a2;
    }
  };
  auto renorm = [&]() {  // fresh measure+apply (R8-proven cadence)
    float mx = fmaxf(fmax4(__builtin_elementwise_max(
                         __builtin_elementwise_max(v0, v1), v2)),
                     1e-30f);
    mx = fmaxf(mx, __shfl_xor(mx, 16));
    mx = fmaxf(mx, __shfl_xor(mx, 32));
    const int ex = ((__float_as_int(mx) >> 23) & 255) - 126;
    const float sc = __int_as_float((127 - ex) << 23);
    v0 *= sc;
    v1 *= sc;
    v2 *= sc;
    cbits += ex;
  };

  // ---- backward prologue: (len&7) steps per column, masked, from global ----
  if (dir == 1 && (p0 | p1)) {
#pragma unroll
    for (int k = 0; k < 7; ++k) {
      const int i0 = k - (7 - p0);  // column-0 backward step idx (<0: inactive)
      const int i1 = k - (7 - p1);
      int row0 = len0 - 1 - i0;
      row0 = (row0 > len0 - 1) ? (len0 - 1) : row0;
      int row1 = len1 - 1 - i1;
      row1 = (row1 > len1 - 1) ? (len1 - 1) : row1;
      const bool act = (n == 0) ? (i0 >= 0) : ((n == 1) ? (i1 >= 0) : false);
      const int myrow = (n == 1) ? row1 : row0;
      const float* rp = ((n == 1) ? eb1 : eb0) + (size_t)myrow * NT;
      const f32x4 x0 = exp4(*(const f32x4*)(rp + 4 * g));
      const f32x4 x1 = exp4(*(const f32x4*)(rp + 16 + 4 * g));
      const f32x4 x2 = exp4(*(const f32x4*)(rp + 32 + 4 * g));
      const f32x4 o0 = v0, o1 = v1, o2 = v2;
      dostep_x(x0, x1, x2);
      v0 = act ? v0 : o0;  // freeze not-yet-started columns
      v1 = act ? v1 : o1;
      v2 = act ? v2 : o2;
    }
    renorm();
  }

  const int nwin = (smax + 31) >> 5;

  // stage window 0: dir0 rows [0,32); dir1 col j rows [lp_j-32, lp_j)
  {
    const float* s0 = dir ? (eb0 + (size_t)(lp0 - 32) * NT) : eb0;
    const float* s1 = dir ? (eb1 + (size_t)(lp1 - 32) * NT) : eb1;
#pragma unroll
    for (int k = 0; k < 6; ++k) {
      gload16(s0 + k * 256 + lane * 4, &sbuf[0][k * 256]);
      gload16(s1 + k * 256 + lane * 4, &sbuf[0][B1OFF + k * 256]);
    }
  }

  for (int c = 0; c < nwin; ++c) {
    asm volatile("s_waitcnt vmcnt(0)" ::: "memory");
    if (c + 1 < nwin) {
      // dir1 staged rows lp_j-32*(c+2) >= lp_j-256 >= 0 (lp >= 256): in-bounds
      const float* s0 = dir ? (eb0 + (size_t)(lp0 - 32 * (c + 2)) * NT)
                            : (eb0 + (size_t)(32 * (c + 1)) * NT);
      const float* s1 = dir ? (eb1 + (size_t)(lp1 - 32 * (c + 2)) * NT)
                            : (eb1 + (size_t)(32 * (c + 1)) * NT);
#pragma unroll
      for (int k = 0; k < 6; ++k) {
        gload16(s0 + k * 256 + lane * 4, &sbuf[(c + 1) & 1][k * 256]);
        gload16(s1 + k * 256 + lane * 4, &sbuf[(c + 1) & 1][B1OFF + k * 256]);
      }
    }
    {  // pre-exp both regions, flat indexing (2-way alias = free)
      float* base2 = &sbuf[c & 1][0];
#pragma unroll
      for (int r = 0; r < 6; ++r) {
        f32x4* pp = (f32x4*)(base2 + r * 256 + lane * 4);
        *pp = exp4(*pp);
        f32x4* p2 = (f32x4*)(base2 + B1OFF + r * 256 + lane * 4);
        *p2 = exp4(*p2);
      }
    }
    const float* wbase = &sbuf[c & 1][myoff];
    const int base = 32 * c;
    const int steps = (smax - base < 32) ? (smax - base) : 32;  // mult of 8
    const int ngr = steps >> 3;
    for (int gi = 0; gi < ngr; ++gi) {
      const int sl0 = gi << 3;
#pragma unroll
      for (int u = 0; u < 8; ++u) {  // static offsets -> cross-step pipelining
        const int loc = dir ? (31 - (sl0 + u)) : (sl0 + u);
        const float* xb = wbase + loc * NT;
        dostep_x(*(const f32x4*)(xb + 4 * g), *(const f32x4*)(xb + 16 + 4 * g),
                 *(const f32x4*)(xb + 32 + 4 * g));
      }
      renorm();
      // branchless group-end latch (stm are multiples of 8 by construction)
      const int cnt = base + sl0 + 8;
      const bool L = (n < 2) && (cnt == my_stm);
      sv0 = L ? v0 : sv0;
      sv1 = L ? v1 : sv1;
      sv2 = L ? v2 : sv2;
      scb = L ? cbits : scb;
    }
  }

  // store latched states (cols 0,1 -> batches b0,b1)
  if (n < 2) {
    const int bb = n ? b1 : b0;
    float* dst = ws + (dir ? WS_WB : WS_QF) + (size_t)bb * 64;
    *(f32x4*)(dst + 4 * g) = sv0;
    *(f32x4*)(dst + 16 + 4 * g) = sv1;
    *(f32x4*)(dst + 32 + 4 * g) = sv2;
    if (g == 0) dst[48] = (float)scb;
  }

  if (dir == 0) {  // gold scores for both batches (R19-verbatim)
#pragma unroll
    for (int which = 0; which < 2; ++which) {
      const int bb = which ? b1 : b0;
      const int ll = which ? len1 : len0;
      const float* eb = which ? eb1 : eb0;
      const int* trow = tags + (size_t)bb * SLEN;
      float gsc = 0.f;
      for (int t = lane; t < ll; t += 64) {
        const int tag = trow[t];
        const int prev = (t == 0) ? TAG_START : trow[t - 1];
        gsc += Tr[tag * NT + prev] + eb[(size_t)t * NT + tag];
      }
#pragma unroll
      for (int d = 32; d >= 1; d >>= 1) gsc += __shfl_xor(gsc, d);
      if (lane == 0) {
        const int last = trow[ll - 1];
        ws[WS_QF + (size_t)bb * 64 + 49] = gsc + Tr[TAG_STOP * NT + last];
      }
    }
  }
}

// Per-batch: logZ - gold = log(q·w) + cbits*ln2 + T[STOP][0] - gold_full.
__global__ __launch_bounds__(64) void crf_combine_kernel(
    const float* __restrict__ Tr, float* __restrict__ ws) {
  const int b = blockIdx.x;
  const int lane = threadIdx.x;
  float p = 0.f;
  if (lane < NT)
    p = ws[WS_QF + (size_t)b * 64 + lane] * ws[WS_WB + (size_t)b * 64 + lane];
#pragma unroll
  for (int d = 32; d >= 1; d >>= 1) p += __shfl_xor(p, d);
  if (lane == 0) {
    const float cb =
        ws[WS_QF + (size_t)b * 64 + 48] + ws[WS_WB + (size_t)b * 64 + 48];
    const float gold = ws[WS_QF + (size_t)b * 64 + 49];
    ws[WS_OUT + b] =
        __logf(p) + cb * 0.69314718055994531f + Tr[TAG_STOP * NT] - gold;
  }
}

// Deterministic tree-mean over B values (no atomics).
__global__ void crf_reduce_kernel(const float* __restrict__ wsrc,
                                  float* __restrict__ out, int nn) {
  const int tid = threadIdx.x;
  float v = (tid < nn) ? wsrc[tid] : 0.f;
#pragma unroll
  for (int d = 32; d >= 1; d >>= 1) v += __shfl_xor(v, d);
  __shared__ float part[16];
  if ((tid & 63) == 0) part[tid >> 6] = v;
  __syncthreads();
  if (tid == 0) {
    float s = 0.f;
    for (int i = 0; i < 16; ++i) s += part[i];
    out[0] = s / (float)nn;
  }
}

extern "C" void kernel_launch(void* const* d_in, const int* in_sizes, int n_in,
                              void* d_out, int out_size, void* d_ws, size_t ws_size,
                              hipStream_t stream) {
  const float* em = (const float*)d_in[0];
  const int* tags = (const int*)d_in[1];
  const int* mask = (const int*)d_in[2];
  const float* Tr = (const float*)d_in[3];
  const int B = in_sizes[0] / (SLEN * NT);  // 1024

  float* ws = (float*)d_ws;  // 132096 floats ≈ 528 KB
  crf_split2_kernel<<<B, 64, 0, stream>>>(em, tags, mask, Tr, ws);
  crf_combine_kernel<<<B, 64, 0, stream>>>(Tr, ws);
  crf_reduce_kernel<<<1, 1024, 0, stream>>>(ws + WS_OUT, (float*)d_out, B);
}